// Round 10
// baseline (401.769 us; speedup 1.0000x reference)
//
#include <hip/hip_runtime.h>
#include <hip/hip_bf16.h>

typedef __hip_bfloat16 bf16;
typedef __attribute__((ext_vector_type(8))) short short8;   // 8 bf16 raw (4 VGPRs)
typedef __attribute__((ext_vector_type(4))) float f32x4;

__device__ __forceinline__ float braw2f(unsigned short u) {
    return __uint_as_float(((unsigned int)u) << 16);
}
__device__ __forceinline__ unsigned short f2braw(float f) {
    bf16 b = __float2bfloat16(f);
    return *(unsigned short*)&b;
}
__device__ __forceinline__ unsigned int pack2(float lo, float hi) {
    return (unsigned int)f2braw(lo) | ((unsigned int)f2braw(hi) << 16);
}

#define LN2F 0.69314718055994531f
// shifted softplus via native HW transcendentals (v_exp/v_log). Stable: arg<=0.
__device__ __forceinline__ float ssp(float x) {
    return fmaxf(x, 0.0f) + __logf(1.0f + __expf(-fabsf(x))) - LN2F;
}

// MFMA linear (verified round 8/9): Y = (ACT? ssp:id)(X @ W^T + B), K=N=128.
template<bool ACT, bool OUT_BF16>
__global__ __launch_bounds__(256) void linear128_mfma_kernel(
    const float* __restrict__ X, const float* __restrict__ W, const float* __restrict__ Bias,
    void* __restrict__ Yv, int n_rows)
{
    __shared__ unsigned short wls[128 * 128];
    __shared__ unsigned short xs[64 * 128];
    __shared__ float bls[128];

    const float4* W4 = (const float4*)W;
    for (int i = threadIdx.x; i < 128 * 32; i += 256) {
        float4 w = W4[i];
        ushort4 s; s.x = f2braw(w.x); s.y = f2braw(w.y); s.z = f2braw(w.z); s.w = f2braw(w.w);
        *(ushort4*)&wls[i * 4] = s;
    }
    if (threadIdx.x < 128) bls[threadIdx.x] = Bias[threadIdx.x];

    const int base = blockIdx.x * 64;
    const float4* X4 = (const float4*)X;
    for (int i = threadIdx.x; i < 64 * 32; i += 256) {
        int r = i >> 5, k4 = i & 31;
        int row = base + r;
        float4 v = (row < n_rows) ? X4[(size_t)row * 32 + k4] : make_float4(0.f, 0.f, 0.f, 0.f);
        ushort4 s; s.x = f2braw(v.x); s.y = f2braw(v.y); s.z = f2braw(v.z); s.w = f2braw(v.w);
        *(ushort4*)&xs[r * 128 + k4 * 4] = s;
    }
    __syncthreads();

    const int wv = threadIdx.x >> 6;
    const int l  = threadIdx.x & 63;
    const int lm = l & 15;
    const int lq = l >> 4;

    short8 a[4];
    #pragma unroll
    for (int kk = 0; kk < 4; ++kk)
        a[kk] = *(const short8*)&xs[(wv * 16 + lm) * 128 + kk * 32 + lq * 8];

    f32x4 acc[8];
    #pragma unroll
    for (int ct = 0; ct < 8; ++ct) {
        f32x4 c = {0.f, 0.f, 0.f, 0.f};
        #pragma unroll
        for (int kk = 0; kk < 4; ++kk) {
            short8 b = *(const short8*)&wls[(ct * 16 + lm) * 128 + kk * 32 + lq * 8];
            c = __builtin_amdgcn_mfma_f32_16x16x32_bf16(a[kk], b, c, 0, 0, 0);
        }
        acc[ct] = c;
    }

    #pragma unroll
    for (int ct = 0; ct < 8; ++ct) {
        int col = ct * 16 + lm;
        float bia = bls[col];
        #pragma unroll
        for (int r = 0; r < 4; ++r) {
            int row = base + wv * 16 + lq * 4 + r;
            if (row < n_rows) {
                float o = acc[ct][r] + bia;
                if (ACT) o = ssp(o);
                if (OUT_BF16) ((unsigned short*)Yv)[(size_t)row * 128 + col] = f2braw(o);
                else          ((float*)Yv)[(size_t)row * 128 + col] = o;
            }
        }
    }
}

// ---- counting sort by idx_i ----

__global__ __launch_bounds__(256) void zero_int_kernel(int* __restrict__ p, int n) {
    int i = blockIdx.x * 256 + threadIdx.x;
    if (i < n) p[i] = 0;
}

__global__ __launch_bounds__(256) void hist_kernel(
    const int* __restrict__ idx_i, int* __restrict__ cnt, int n_pairs, int n_atoms)
{
    for (int p = blockIdx.x * 256 + threadIdx.x; p < n_pairs; p += gridDim.x * 256) {
        int ai = idx_i[p];
        if ((unsigned)ai < (unsigned)n_atoms) atomicAdd(&cnt[ai], 1);
    }
}

__global__ __launch_bounds__(1024) void scan1_kernel(
    const int* __restrict__ cnt, int* __restrict__ offs, int* __restrict__ partials, int n)
{
    __shared__ int sm[1024];
    int t = threadIdx.x, idx = blockIdx.x * 1024 + t;
    int v = (idx < n) ? cnt[idx] : 0;
    sm[t] = v;
    __syncthreads();
    #pragma unroll
    for (int d = 1; d < 1024; d <<= 1) {
        int tmp = (t >= d) ? sm[t - d] : 0;
        __syncthreads();
        sm[t] += tmp;
        __syncthreads();
    }
    if (idx < n) offs[idx] = sm[t] - v;
    if (t == 1023) partials[blockIdx.x] = sm[1023];
}

__global__ __launch_bounds__(64) void scan2_kernel(
    int* __restrict__ partials, int* __restrict__ offs, int nb, int n)
{
    __shared__ int sm[64];
    int t = threadIdx.x;
    int v = (t < nb) ? partials[t] : 0;
    sm[t] = v;
    __syncthreads();
    #pragma unroll
    for (int d = 1; d < 64; d <<= 1) {
        int tmp = (t >= d) ? sm[t - d] : 0;
        __syncthreads();
        sm[t] += tmp;
        __syncthreads();
    }
    if (t < nb) partials[t] = sm[t] - v;
    if (t == 63) offs[n] = sm[63];
}

__global__ __launch_bounds__(1024) void scan3_kernel(
    int* __restrict__ offs, int* __restrict__ cur, const int* __restrict__ partials, int n)
{
    int idx = blockIdx.x * 1024 + threadIdx.x;
    if (idx < n) {
        int o = offs[idx] + partials[blockIdx.x];
        offs[idx] = o;
        cur[idx] = o;
    }
}

// ---------- PAYLOAD PATH: physically sort pair payload (48 B/pair) ----------
__global__ __launch_bounds__(256) void scatter_pay_kernel(
    const float* __restrict__ f_ij, const int* __restrict__ idx_i, const int* __restrict__ idx_j,
    const float* __restrict__ rcut, int* __restrict__ cur, uint4* __restrict__ pay,
    int n_pairs, int n_atoms)
{
    for (int p = blockIdx.x * 256 + threadIdx.x; p < n_pairs; p += gridDim.x * 256) {
        int ai = idx_i[p];
        if ((unsigned)ai >= (unsigned)n_atoms) continue;
        int pos = atomicAdd(&cur[ai], 1);
        const float4* fr = (const float4*)(f_ij + (size_t)p * 20);
        float4 f0 = fr[0], f1 = fr[1], f2 = fr[2], f3 = fr[3], f4 = fr[4];
        uint4 q0, q1, q2;
        q0.x = pack2(f0.x, f0.y); q0.y = pack2(f0.z, f0.w);
        q0.z = pack2(f1.x, f1.y); q0.w = pack2(f1.z, f1.w);
        q1.x = pack2(f2.x, f2.y); q1.y = pack2(f2.z, f2.w);
        q1.z = pack2(f3.x, f3.y); q1.w = pack2(f3.z, f3.w);
        q2.x = pack2(f4.x, f4.y); q2.y = pack2(f4.z, f4.w);
        q2.z = (unsigned int)idx_j[p];
        q2.w = __float_as_uint(rcut[p]);
        uint4* dst = pay + (size_t)pos * 3;
        dst[0] = q0; dst[1] = q1; dst[2] = q2;
    }
}

// One pair's filter+modulate contribution for this lane's 2 channels.
__device__ __forceinline__ void pair_contrib(
    uint4 q0, uint4 q1, uint4 q2,
    const float* __restrict__ w0, const float* __restrict__ w1,
    float b0, float b1, const unsigned int* __restrict__ hb32, int lane,
    float& acc0, float& acc1)
{
    unsigned int h = hb32[(size_t)(int)q2.z * 64 + lane];   // issue gather early
    unsigned int u[10] = {q0.x,q0.y,q0.z,q0.w,q1.x,q1.y,q1.z,q1.w,q2.x,q2.y};
    float a0 = b0, a1 = b1;
    #pragma unroll
    for (int r = 0; r < 10; ++r) {
        float lo = __uint_as_float(u[r] << 16);
        float hi = __uint_as_float(u[r] & 0xffff0000u);
        a0 += lo * w0[2*r];     a1 += lo * w1[2*r];
        a0 += hi * w0[2*r + 1]; a1 += hi * w1[2*r + 1];
    }
    float rc = __uint_as_float(q2.w);
    float wv0 = ssp(a0) * rc, wv1 = ssp(a1) * rc;
    acc0 += __uint_as_float(h << 16) * wv0;
    acc1 += __uint_as_float(h & 0xffff0000u) * wv1;
}

// Persistent-wave segment reduction (round-10 rework):
//  - grid-stride over atoms: W_f register arrays loaded ONCE per wave lifetime
//    (was: once per atom => 40 loads x 40k waves + block churn => 34% occupancy)
//  - __launch_bounds__(256,4): VGPR cap 128 so w0/w1 + 4-pair payload stay in
//    registers (round-9 VGPR=64 => spill/remat => ~257 VALU instr/pair vs ~90)
//  - 4 independent payload->h chains per iteration to hide L2/LLC latency.
__global__ __launch_bounds__(256, 4) void segment_pay_kernel(
    const uint4* __restrict__ pay, const float* __restrict__ W_f,
    const float* __restrict__ b_f, const unsigned int* __restrict__ hb32,
    const int* __restrict__ offs, float* __restrict__ agg, int n_atoms)
{
    const int lane = threadIdx.x & 63;
    const int wid  = (blockIdx.x * 256 + threadIdx.x) >> 6;
    const int nw   = (gridDim.x * 256) >> 6;

    const int c0 = 2 * lane;
    float w0[20], w1[20];
    #pragma unroll
    for (int r = 0; r < 20; ++r) {
        w0[r] = W_f[c0 * 20 + r];
        w1[r] = W_f[(c0 + 1) * 20 + r];
    }
    const float b0 = b_f[c0], b1 = b_f[c0 + 1];

    for (int atom = wid; atom < n_atoms; atom += nw) {
        const int cs = offs[atom], ce = offs[atom + 1];
        float acc0 = 0.f, acc1 = 0.f;

        int s = cs;
        for (; s + 4 <= ce; s += 4) {
            const uint4* P = pay + (size_t)s * 3;
            uint4 qa0 = P[0],  qa1 = P[1],  qa2 = P[2];
            uint4 qb0 = P[3],  qb1 = P[4],  qb2 = P[5];
            uint4 qc0 = P[6],  qc1 = P[7],  qc2 = P[8];
            uint4 qd0 = P[9],  qd1 = P[10], qd2 = P[11];
            pair_contrib(qa0, qa1, qa2, w0, w1, b0, b1, hb32, lane, acc0, acc1);
            pair_contrib(qb0, qb1, qb2, w0, w1, b0, b1, hb32, lane, acc0, acc1);
            pair_contrib(qc0, qc1, qc2, w0, w1, b0, b1, hb32, lane, acc0, acc1);
            pair_contrib(qd0, qd1, qd2, w0, w1, b0, b1, hb32, lane, acc0, acc1);
        }
        for (; s < ce; ++s) {
            const uint4* P = pay + (size_t)s * 3;
            uint4 q0 = P[0], q1 = P[1], q2 = P[2];
            pair_contrib(q0, q1, q2, w0, w1, b0, b1, hb32, lane, acc0, acc1);
        }

        *(float2*)&agg[(size_t)atom * 128 + c0] = make_float2(acc0, acc1);
    }
}

// ---------- FALLBACK PATH (round-8, proven; ws < payload need) ----------
__global__ __launch_bounds__(256) void scatter_kernel(
    const int* __restrict__ idx_i, int* __restrict__ cur, int* __restrict__ perm,
    int n_pairs, int n_atoms)
{
    for (int p = blockIdx.x * 256 + threadIdx.x; p < n_pairs; p += gridDim.x * 256) {
        int ai = idx_i[p];
        if ((unsigned)ai < (unsigned)n_atoms) {
            int pos = atomicAdd(&cur[ai], 1);
            perm[pos] = p;
        }
    }
}

__global__ __launch_bounds__(256) void segment_kernel(
    const float* __restrict__ f_ij, const int* __restrict__ idx_j,
    const float* __restrict__ rcut, const float* __restrict__ W_f,
    const float* __restrict__ b_f, const unsigned short* __restrict__ hb,
    const int* __restrict__ offs, const int* __restrict__ perm,
    float* __restrict__ agg, int n_atoms)
{
    const int wave = (blockIdx.x * 256 + threadIdx.x) >> 6;
    const int lane = threadIdx.x & 63;
    if (wave >= n_atoms) return;

    float w0[20], w1[20];
    #pragma unroll
    for (int r = 0; r < 20; ++r) {
        w0[r] = W_f[lane * 20 + r];
        w1[r] = W_f[(lane + 64) * 20 + r];
    }
    const float b0 = b_f[lane], b1 = b_f[lane + 64];

    const int cs = offs[wave], ce = offs[wave + 1];
    float acc0 = 0.f, acc1 = 0.f;

    for (int s = cs; s < ce; ++s) {
        int p = perm[s];
        int aj = idx_j[p];
        float rc = rcut[p];
        const float4* fr = (const float4*)(f_ij + (size_t)p * 20);
        float a0 = b0, a1 = b1;
        #pragma unroll
        for (int q = 0; q < 5; ++q) {
            float4 fv = fr[q];
            a0 += fv.x * w0[4*q+0]; a1 += fv.x * w1[4*q+0];
            a0 += fv.y * w0[4*q+1]; a1 += fv.y * w1[4*q+1];
            a0 += fv.z * w0[4*q+2]; a1 += fv.z * w1[4*q+2];
            a0 += fv.w * w0[4*q+3]; a1 += fv.w * w1[4*q+3];
        }
        float wv0 = ssp(a0) * rc, wv1 = ssp(a1) * rc;
        acc0 += braw2f(hb[(size_t)aj * 128 + lane]) * wv0;
        acc1 += braw2f(hb[(size_t)aj * 128 + 64 + lane]) * wv1;
    }

    agg[(size_t)wave * 128 + lane]      = acc0;
    agg[(size_t)wave * 128 + 64 + lane] = acc1;
}

static inline size_t align_up(size_t v, size_t a) { return (v + a - 1) & ~(a - 1); }

extern "C" void kernel_launch(void* const* d_in, const int* in_sizes, int n_in,
                              void* d_out, int out_size, void* d_ws, size_t ws_size,
                              hipStream_t stream) {
    const float* x     = (const float*)d_in[0];
    const float* f_ij  = (const float*)d_in[1];
    const int*   idx_i = (const int*)d_in[2];
    const int*   idx_j = (const int*)d_in[3];
    const float* rcut  = (const float*)d_in[4];
    const float* W_in  = (const float*)d_in[5];
    const float* b_in  = (const float*)d_in[6];
    const float* W_f   = (const float*)d_in[7];
    const float* b_f   = (const float*)d_in[8];
    const float* W_out = (const float*)d_in[9];
    const float* b_out = (const float*)d_in[10];

    const int n_atoms = in_sizes[0] / 128;   // 40000
    const int n_pairs = in_sizes[2];         // 640000
    const int nscan = (n_atoms + 1023) / 1024;
    const int mfma_grid = (n_atoms + 63) / 64;

    size_t off_hb   = 0;
    size_t off_offs = align_up(off_hb + (size_t)n_atoms * 128 * 2, 16);
    size_t off_cur  = align_up(off_offs + (size_t)(n_atoms + 1) * 4, 16);
    size_t off_part = align_up(off_cur + (size_t)n_atoms * 4, 16);
    size_t off_pay  = align_up(off_part + (size_t)nscan * 4, 64);
    size_t need_pay = off_pay + (size_t)n_pairs * 48;      // ~41.3 MB (proven fits, round 9)

    if (ws_size >= need_pay) {
        unsigned short* hb = (unsigned short*)((char*)d_ws + off_hb);
        int*  offs = (int*)((char*)d_ws + off_offs);
        int*  cur  = (int*)((char*)d_ws + off_cur);
        int*  part = (int*)((char*)d_ws + off_part);
        uint4* pay = (uint4*)((char*)d_ws + off_pay);
        float* agg = (float*)d_out;

        linear128_mfma_kernel<false, true><<<dim3(mfma_grid), dim3(256), 0, stream>>>(
            x, W_in, b_in, (void*)hb, n_atoms);

        zero_int_kernel<<<dim3((n_atoms + 255) / 256), dim3(256), 0, stream>>>(cur, n_atoms);
        hist_kernel<<<dim3(1024), dim3(256), 0, stream>>>(idx_i, cur, n_pairs, n_atoms);
        scan1_kernel<<<dim3(nscan), dim3(1024), 0, stream>>>(cur, offs, part, n_atoms);
        scan2_kernel<<<dim3(1), dim3(64), 0, stream>>>(part, offs, nscan, n_atoms);
        scan3_kernel<<<dim3(nscan), dim3(1024), 0, stream>>>(offs, cur, part, n_atoms);
        scatter_pay_kernel<<<dim3(1024), dim3(256), 0, stream>>>(
            f_ij, idx_i, idx_j, rcut, cur, pay, n_pairs, n_atoms);

        segment_pay_kernel<<<dim3(1024), dim3(256), 0, stream>>>(
            pay, W_f, b_f, (const unsigned int*)hb, offs, agg, n_atoms);

        linear128_mfma_kernel<true, false><<<dim3(mfma_grid), dim3(256), 0, stream>>>(
            agg, W_out, b_out, d_out, n_atoms);
    } else {
        size_t o_h    = 0;
        size_t o_offs = o_h + (size_t)n_atoms * 128 * 2;
        size_t o_cur  = o_offs + (size_t)(n_atoms + 1) * 4;
        size_t o_perm = o_cur + (size_t)n_atoms * 4;
        size_t o_part = o_perm + (size_t)n_pairs * 4;
        unsigned short* hb = (unsigned short*)((char*)d_ws + o_h);
        int* offs = (int*)((char*)d_ws + o_offs);
        int* cur  = (int*)((char*)d_ws + o_cur);
        int* perm = (int*)((char*)d_ws + o_perm);
        int* part = (int*)((char*)d_ws + o_part);
        float* agg = (float*)d_out;

        linear128_mfma_kernel<false, true><<<dim3(mfma_grid), dim3(256), 0, stream>>>(
            x, W_in, b_in, (void*)hb, n_atoms);

        zero_int_kernel<<<dim3((n_atoms + 255) / 256), dim3(256), 0, stream>>>(cur, n_atoms);
        hist_kernel<<<dim3(1024), dim3(256), 0, stream>>>(idx_i, cur, n_pairs, n_atoms);
        scan1_kernel<<<dim3(nscan), dim3(1024), 0, stream>>>(cur, offs, part, n_atoms);
        scan2_kernel<<<dim3(1), dim3(64), 0, stream>>>(part, offs, nscan, n_atoms);
        scan3_kernel<<<dim3(nscan), dim3(1024), 0, stream>>>(offs, cur, part, n_atoms);
        scatter_kernel<<<dim3(1024), dim3(256), 0, stream>>>(idx_i, cur, perm, n_pairs, n_atoms);

        segment_kernel<<<dim3((n_atoms + 3) / 4), dim3(256), 0, stream>>>(
            f_ij, idx_j, rcut, W_f, b_f, hb, offs, perm, agg, n_atoms);

        linear128_mfma_kernel<true, false><<<dim3(mfma_grid), dim3(256), 0, stream>>>(
            agg, W_out, b_out, d_out, n_atoms);
    }
}